// Round 3
// baseline (253.788 us; speedup 1.0000x reference)
//
#include <hip/hip_runtime.h>

#define N_SEQ 2048
#define S_LEN 4096
#define W_SEQ 64                               // u64 words per sequence (S/64)
#define TILE 64
#define T_TILES (N_SEQ / TILE)                 // 32
#define NBLK (T_TILES * (T_TILES + 1) / 2)     // 528 upper-triangle tiles
#define CHUNK 16                               // words per LDS K-chunk
#define STRIDE 17                              // padded LDS row stride (odd -> conflict-free)
#define NSITES (N_SEQ * S_LEN)                 // 8388608
#define ENC_BLOCKS 4096
#define ENC_THREADS (ENC_BLOCKS * 256)         // 1048576 -> 8 sites/thread

// ---------------- Kernel 1: encode + zprep + init ----------------
// one-hot fp32 -> 2-bit packed bit-planes (wave __ballot), plus tiny z-prep
// and ws-scalar init (acc, counter). Kernel boundary orders these for K2.
__global__ __launch_bounds__(256) void encode_kernel(const float4* __restrict__ data,
                                                     const float* __restrict__ table,
                                                     ulonglong2* __restrict__ codes,
                                                     float4* __restrict__ zbuf,
                                                     double* __restrict__ acc,
                                                     unsigned* __restrict__ counter) {
    int tid = threadIdx.x;
    int gtid = blockIdx.x * 256 + tid;

    if (gtid == 0) { *acc = 0.0; *counter = 0u; }   // ws is 0xAA-poisoned every call

    if (gtid < N_SEQ) {
        float vx = table[2 * gtid], vy = table[2 * gtid + 1];
        float n = sqrtf(vx * vx + vy * vy);
        float f = tanhf(n) / fmaxf(n, 1e-12f);
        float zx = vx * f, zy = vy * f;
        float omn = 1.0f - (zx * zx + zy * zy);      // 1 - ||z||^2
        zbuf[gtid] = make_float4(zx, zy, omn, 0.0f);
    }

    // grid-stride; stride is a multiple of 64 so each wave maps to one u64 word
    for (int t = gtid; t < NSITES; t += ENC_THREADS) {
        float4 v = data[t];                          // coalesced 16B/lane
        int c = (int)(v.y + 2.0f * v.z + 3.0f * v.w + 0.5f);   // exact token recovery
        unsigned long long lo = __ballot(c & 1);
        unsigned long long hi = __ballot(c & 2);
        if ((tid & 63) == 0) {
            ulonglong2 e; e.x = lo; e.y = hi;
            codes[t >> 6] = e;
        }
    }
}

// ---------------- Kernel 2: pairwise popcount-hamming + hyperbolic + full reduce ----
// 64x64 pair tile per block; 16x16 threads, each owns 4x4 pairs. Last block
// (ticket pattern, device-scope atomics) writes the final scalar.
__global__ __launch_bounds__(256) void pairs_kernel(const ulonglong2* __restrict__ codes,
                                                    const float4* __restrict__ zbuf,
                                                    const float* __restrict__ log_scale,
                                                    double* __restrict__ acc,
                                                    unsigned* __restrict__ counter,
                                                    float* __restrict__ out) {
    __shared__ ulonglong2 As[TILE * STRIDE];
    __shared__ ulonglong2 Bs[TILE * STRIDE];
    __shared__ float wsum[4];

    int bid = blockIdx.x;
    // triangle mapping: bid = r*(r+1)/2 + c, c <= r (i-tile = c, j-tile = r)
    int r = (int)((sqrtf(8.0f * (float)bid + 1.0f) - 1.0f) * 0.5f);
    while ((r + 1) * (r + 2) / 2 <= bid) ++r;
    while (r * (r + 1) / 2 > bid) --r;
    int c = bid - r * (r + 1) / 2;
    int i0 = c * TILE, j0 = r * TILE;

    int tid = threadIdx.x;
    int tx = tid & 15, ty = tid >> 4;

    int mis[4][4];
#pragma unroll
    for (int k = 0; k < 4; ++k)
#pragma unroll
        for (int l = 0; l < 4; ++l) mis[k][l] = 0;

    for (int cc = 0; cc < W_SEQ / CHUNK; ++cc) {
#pragma unroll
        for (int p = 0; p < 4; ++p) {
            int e = tid + p * 256;                   // 0..1023
            int row = e >> 4, w = e & 15;
            As[row * STRIDE + w] = codes[(i0 + row) * W_SEQ + cc * CHUNK + w];
            Bs[row * STRIDE + w] = codes[(j0 + row) * W_SEQ + cc * CHUNK + w];
        }
        __syncthreads();
#pragma unroll
        for (int w = 0; w < CHUNK; ++w) {
            ulonglong2 a[4], bb[4];
#pragma unroll
            for (int k = 0; k < 4; ++k) a[k] = As[(ty + 16 * k) * STRIDE + w];
#pragma unroll
            for (int l = 0; l < 4; ++l) bb[l] = Bs[(tx + 16 * l) * STRIDE + w];
#pragma unroll
            for (int k = 0; k < 4; ++k)
#pragma unroll
                for (int l = 0; l < 4; ++l)
                    mis[k][l] += __popcll((a[k].x ^ bb[l].x) | (a[k].y ^ bb[l].y));
        }
        __syncthreads();
    }

    // fused epilogue: exact hamming, hyperbolic dist, symmetry-weighted sq-diff
    float scale = expf(log_scale[0]);
    const float inv_s = 1.0f / (float)S_LEN;
    float local = 0.0f;
#pragma unroll
    for (int k = 0; k < 4; ++k) {
        int i = i0 + ty + 16 * k;
        float4 zi = zbuf[i];
#pragma unroll
        for (int l = 0; l < 4; ++l) {
            int j = j0 + tx + 16 * l;
            float4 zj = zbuf[j];
            float ham = (float)mis[k][l] * inv_s;
            float dx = zi.x - zj.x, dy = zi.y - zj.y;
            float dsq = dx * dx + dy * dy;
            float arg = 1.0f + 2.0f * dsq / (zi.z * zj.z);
            arg = fmaxf(arg, 1.0f + 1e-7f);
            float dist = acoshf(arg) * scale;
            float d = ham - dist;
            float wgt = (i < j) ? 2.0f : (i == j ? 1.0f : 0.0f);
            local += wgt * d * d;
        }
    }

#pragma unroll
    for (int off = 32; off > 0; off >>= 1) local += __shfl_down(local, off);
    if ((tid & 63) == 0) wsum[tid >> 6] = local;
    __syncthreads();

    if (tid == 0) {
        double part = (double)(wsum[0] + wsum[1] + wsum[2] + wsum[3]);
        atomicAdd(acc, part);                        // device-scope by default
        __threadfence();                             // release before ticket
        unsigned prev = atomicAdd(counter, 1u);
        if (prev == NBLK - 1) {
            // last block: coherent read of the total via device-scope RMW
            double tot = atomicAdd(acc, 0.0);
            out[0] = (float)(tot / ((double)N_SEQ * (double)N_SEQ));
        }
    }
}

extern "C" void kernel_launch(void* const* d_in, const int* in_sizes, int n_in,
                              void* d_out, int out_size, void* d_ws, size_t ws_size,
                              hipStream_t stream) {
    const float4* data      = (const float4*)d_in[0];  // N x S x A fp32 one-hot
    const float*  table     = (const float*)d_in[1];   // N x 2
    const float*  log_scale = (const float*)d_in[2];   // scalar
    float* out = (float*)d_out;

    char* ws = (char*)d_ws;
    ulonglong2* codes   = (ulonglong2*)ws;                                       // 2 MB
    float4*     zbuf    = (float4*)(ws + (size_t)N_SEQ * W_SEQ * sizeof(ulonglong2));
    double*     acc     = (double*)((char*)zbuf + (size_t)N_SEQ * sizeof(float4));
    unsigned*   counter = (unsigned*)((char*)acc + sizeof(double));

    encode_kernel<<<ENC_BLOCKS, 256, 0, stream>>>(data, table, codes, zbuf, acc, counter);
    pairs_kernel <<<NBLK,       256, 0, stream>>>(codes, zbuf, log_scale, acc, counter, out);
}

// Round 5
// 245.052 us; speedup vs baseline: 1.0356x; 1.0356x over previous
//
#include <hip/hip_runtime.h>

#define N_SEQ 2048
#define S_LEN 4096
#define W_SEQ 64                               // u64 words per sequence (S/64)
#define TILE 64
#define T_TILES (N_SEQ / TILE)                 // 32
#define NBLK (T_TILES * (T_TILES + 1) / 2)     // 528 upper-triangle tiles
#define CHUNK 16                               // words per LDS K-chunk
#define STRIDE 17                              // padded LDS row stride (odd -> conflict-free)
#define NSITES (N_SEQ * S_LEN)                 // 8388608
#define ENC_BLOCKS 4096
#define ENC_THREADS (ENC_BLOCKS * 256)         // 1048576 -> 8 sites/thread

typedef float vfloat4 __attribute__((ext_vector_type(4)));   // native vec for nontemporal builtin

// ---------------- Kernel 1: encode + zprep + init ----------------
// one-hot fp32 -> 2-bit packed bit-planes (wave __ballot), plus tiny z-prep
// and ws-scalar init (acc, counter). Kernel boundary orders these for K2.
__global__ __launch_bounds__(256) void encode_kernel(const vfloat4* __restrict__ data,
                                                     const float* __restrict__ table,
                                                     ulonglong2* __restrict__ codes,
                                                     float4* __restrict__ zbuf,
                                                     double* __restrict__ acc,
                                                     unsigned* __restrict__ counter) {
    int tid = threadIdx.x;
    int gtid = blockIdx.x * 256 + tid;

    if (gtid == 0) { *acc = 0.0; *counter = 0u; }   // ws is 0xAA-poisoned every call

    if (gtid < N_SEQ) {
        float vx = table[2 * gtid], vy = table[2 * gtid + 1];
        float n = sqrtf(vx * vx + vy * vy);
        float f = tanhf(n) / fmaxf(n, 1e-12f);
        float zx = vx * f, zy = vy * f;
        float omn = 1.0f - (zx * zx + zy * zy);      // 1 - ||z||^2
        zbuf[gtid] = make_float4(zx, zy, omn, 0.0f);
    }

    // grid-stride; stride is a multiple of 64 so each wave maps to one u64 word.
    // tokens: 0->x, 1->y, 2->z, 3->w  =>  lo-plane = y|w, hi-plane = z|w.
#pragma unroll
    for (int it = 0; it < NSITES / ENC_THREADS; ++it) {
        int t = gtid + it * ENC_THREADS;
        vfloat4 v = __builtin_nontemporal_load(&data[t]);   // read-once 134 MB stream
        unsigned long long lo = __ballot(v.y + v.w > 0.5f);
        unsigned long long hi = __ballot(v.z + v.w > 0.5f);
        if ((tid & 63) == 0) {
            ulonglong2 e; e.x = lo; e.y = hi;
            codes[t >> 6] = e;
        }
    }
}

// ---------------- Kernel 2: pairwise popcount-hamming + hyperbolic + full reduce ----
// 64x64 pair tile per block; 16x16 threads, each owns 4x4 pairs. Last block
// (ticket pattern, device-scope atomics) writes the final scalar.
// __launch_bounds__(256,4): 4 waves/SIMD -> 4 blocks/CU resident (LDS 35KB*4<=160KB),
// so staging of one block overlaps compute of co-resident blocks (528 tiles on
// 256 CUs -> 16 CUs carry 3 tiles; overlap softens that tail).
__global__ __launch_bounds__(256, 4) void pairs_kernel(const ulonglong2* __restrict__ codes,
                                                       const float4* __restrict__ zbuf,
                                                       const float* __restrict__ log_scale,
                                                       double* __restrict__ acc,
                                                       unsigned* __restrict__ counter,
                                                       float* __restrict__ out) {
    __shared__ ulonglong2 As[TILE * STRIDE];
    __shared__ ulonglong2 Bs[TILE * STRIDE];
    __shared__ float wsum[4];

    int bid = blockIdx.x;
    // triangle mapping: bid = r*(r+1)/2 + c, c <= r (i-tile = c, j-tile = r)
    int r = (int)((sqrtf(8.0f * (float)bid + 1.0f) - 1.0f) * 0.5f);
    while ((r + 1) * (r + 2) / 2 <= bid) ++r;
    while (r * (r + 1) / 2 > bid) --r;
    int c = bid - r * (r + 1) / 2;
    int i0 = c * TILE, j0 = r * TILE;

    int tid = threadIdx.x;
    int tx = tid & 15, ty = tid >> 4;

    // hoisted staging addresses: entry e = tid + p*256 -> row = e>>4, w = e&15
    int srow = tid >> 4, sw = tid & 15;
    const ulonglong2* gA = codes + (size_t)(i0 + srow) * W_SEQ + sw;
    const ulonglong2* gB = codes + (size_t)(j0 + srow) * W_SEQ + sw;
    ulonglong2* lA = As + srow * STRIDE + sw;
    ulonglong2* lB = Bs + srow * STRIDE + sw;

    int mis[4][4];
#pragma unroll
    for (int k = 0; k < 4; ++k)
#pragma unroll
        for (int l = 0; l < 4; ++l) mis[k][l] = 0;

    for (int cc = 0; cc < W_SEQ / CHUNK; ++cc) {
#pragma unroll
        for (int p = 0; p < 4; ++p) {              // +16 rows per pass
            lA[p * 16 * STRIDE] = gA[(size_t)(p * 16) * W_SEQ + cc * CHUNK];
            lB[p * 16 * STRIDE] = gB[(size_t)(p * 16) * W_SEQ + cc * CHUNK];
        }
        __syncthreads();
#pragma unroll
        for (int w = 0; w < CHUNK; ++w) {
            ulonglong2 a[4], bb[4];
#pragma unroll
            for (int k = 0; k < 4; ++k) a[k] = As[(ty + 16 * k) * STRIDE + w];
#pragma unroll
            for (int l = 0; l < 4; ++l) bb[l] = Bs[(tx + 16 * l) * STRIDE + w];
#pragma unroll
            for (int k = 0; k < 4; ++k)
#pragma unroll
                for (int l = 0; l < 4; ++l)
                    mis[k][l] += __popcll((a[k].x ^ bb[l].x) | (a[k].y ^ bb[l].y));
        }
        __syncthreads();
    }

    // fused epilogue: exact hamming, hyperbolic dist, symmetry-weighted sq-diff
    float scale = expf(log_scale[0]);
    const float inv_s = 1.0f / (float)S_LEN;
    float local = 0.0f;
#pragma unroll
    for (int k = 0; k < 4; ++k) {
        int i = i0 + ty + 16 * k;
        float4 zi = zbuf[i];
#pragma unroll
        for (int l = 0; l < 4; ++l) {
            int j = j0 + tx + 16 * l;
            float4 zj = zbuf[j];
            float ham = (float)mis[k][l] * inv_s;
            float dx = zi.x - zj.x, dy = zi.y - zj.y;
            float dsq = dx * dx + dy * dy;
            float arg = 1.0f + 2.0f * dsq / (zi.z * zj.z);
            arg = fmaxf(arg, 1.0f + 1e-7f);
            float dist = acoshf(arg) * scale;
            float d = ham - dist;
            float wgt = (i < j) ? 2.0f : (i == j ? 1.0f : 0.0f);
            local += wgt * d * d;
        }
    }

#pragma unroll
    for (int off = 32; off > 0; off >>= 1) local += __shfl_down(local, off);
    if ((tid & 63) == 0) wsum[tid >> 6] = local;
    __syncthreads();

    if (tid == 0) {
        double part = (double)(wsum[0] + wsum[1] + wsum[2] + wsum[3]);
        atomicAdd(acc, part);                        // device-scope by default
        __threadfence();                             // release before ticket
        unsigned prev = atomicAdd(counter, 1u);
        if (prev == NBLK - 1) {
            // last block: coherent read of the total via device-scope RMW
            double tot = atomicAdd(acc, 0.0);
            out[0] = (float)(tot / ((double)N_SEQ * (double)N_SEQ));
        }
    }
}

extern "C" void kernel_launch(void* const* d_in, const int* in_sizes, int n_in,
                              void* d_out, int out_size, void* d_ws, size_t ws_size,
                              hipStream_t stream) {
    const vfloat4* data     = (const vfloat4*)d_in[0]; // N x S x A fp32 one-hot
    const float*  table     = (const float*)d_in[1];   // N x 2
    const float*  log_scale = (const float*)d_in[2];   // scalar
    float* out = (float*)d_out;

    char* ws = (char*)d_ws;
    ulonglong2* codes   = (ulonglong2*)ws;                                       // 2 MB
    float4*     zbuf    = (float4*)(ws + (size_t)N_SEQ * W_SEQ * sizeof(ulonglong2));
    double*     acc     = (double*)((char*)zbuf + (size_t)N_SEQ * sizeof(float4));
    unsigned*   counter = (unsigned*)((char*)acc + sizeof(double));

    encode_kernel<<<ENC_BLOCKS, 256, 0, stream>>>(data, table, codes, zbuf, acc, counter);
    pairs_kernel <<<NBLK,       256, 0, stream>>>(codes, zbuf, log_scale, acc, counter, out);
}